// Round 1
// baseline (730.463 us; speedup 1.0000x reference)
//
#include <hip/hip_runtime.h>
#include <math.h>

#define BATCH 4096
#define IDIM 78
#define DM 256
#define DI 1024
#define NL 4

__device__ __forceinline__ float siluf(float v){ return v / (1.0f + __expf(-v)); }
__device__ __forceinline__ float softplusf(float v){ return (v > 20.0f) ? v : log1pf(__expf(v)); }

// ---------- proj_in: h = x @ Wp + bp  (4096x78 @ 78x256) ----------
__global__ __launch_bounds__(256) void k_proj_in(const float* __restrict__ x,
    const float* __restrict__ Wp, const float* __restrict__ bp, float* __restrict__ h){
  int b = blockIdx.x, t = threadIdx.x;
  __shared__ float xs[IDIM];
  if (t < IDIM) xs[t] = x[b*IDIM + t];
  __syncthreads();
  float acc = bp[t];
  #pragma unroll
  for (int k=0;k<IDIM;k++) acc = fmaf(xs[k], Wp[k*DM + t], acc);
  h[b*DM + t] = acc;
}

// ---------- rmsnorm: xn = h * rsqrt(mean(h^2)+eps) * nw ----------
__global__ __launch_bounds__(256) void k_rmsnorm(const float* __restrict__ h,
    const float* __restrict__ nw, float* __restrict__ xn){
  int b = blockIdx.x, t = threadIdx.x;
  float v = h[b*DM + t];
  float ss = v*v;
  #pragma unroll
  for (int o=32;o>0;o>>=1) ss += __shfl_down(ss, o);
  __shared__ float red[4];
  if ((t&63)==0) red[t>>6] = ss;
  __syncthreads();
  float tot = red[0]+red[1]+red[2]+red[3];
  float sc = rsqrtf(tot*(1.0f/DM) + 1e-5f);
  xn[b*DM + t] = v*sc*nw[t];
}

// ---------- generic fp32 tiled GEMM, 256 threads, BM=TM*16, BN=64, TN=4 ----------
// EPI=0: conv/silu epilogue -> xi (c<DI) / silu -> sz (c>=DI)
// EPI=1: out0[r*DM+c] += acc   (residual accumulate into h)
template<int BK, int TM, int EPI>
__global__ __launch_bounds__(256) void k_gemm(
    const float* __restrict__ A, const float* __restrict__ B,
    int K, int N,
    const float* __restrict__ aux0, const float* __restrict__ aux1,
    float* __restrict__ out0, float* __restrict__ out1)
{
  constexpr int BM = TM*16;
  constexpr int BN = 64;
  constexpr int TN = 4;
  int row0 = blockIdx.x*BM, col0 = blockIdx.y*BN;
  int t = threadIdx.x, tx = t&15, ty = t>>4;
  __shared__ __align__(16) float As[BK][BM+4];
  __shared__ __align__(16) float Bs[BK][BN+4];
  float acc[TM][TN] = {};
  for (int k0=0;k0<K;k0+=BK){
    // stage A tile (BM x BK), stored transposed As[k][m]
    for (int idx=t; idx < BM*(BK/4); idx += 256){
      int m = idx/(BK/4), kf = (idx%(BK/4))*4;
      float4 v = *(const float4*)(A + (size_t)(row0+m)*K + k0 + kf);
      As[kf+0][m]=v.x; As[kf+1][m]=v.y; As[kf+2][m]=v.z; As[kf+3][m]=v.w;
    }
    // stage B tile (BK x BN)
    for (int idx=t; idx < BK*(BN/4); idx += 256){
      int kk = idx/(BN/4), bn = (idx%(BN/4))*4;
      *(float4*)&Bs[kk][bn] = *(const float4*)(B + (size_t)(k0+kk)*N + col0 + bn);
    }
    __syncthreads();
    #pragma unroll
    for (int kk=0;kk<BK;kk++){
      float av[TM], bv[TN];
      #pragma unroll
      for (int i=0;i<TM;i++) av[i] = As[kk][ty*TM+i];
      #pragma unroll
      for (int j=0;j<TN;j++) bv[j] = Bs[kk][tx*TN+j];
      #pragma unroll
      for (int i=0;i<TM;i++)
        #pragma unroll
        for (int j=0;j<TN;j++) acc[i][j] = fmaf(av[i], bv[j], acc[i][j]);
    }
    __syncthreads();
  }
  #pragma unroll
  for (int i=0;i<TM;i++){
    int r = row0 + ty*TM + i;
    #pragma unroll
    for (int j=0;j<TN;j++){
      int c = col0 + tx*TN + j;
      float v = acc[i][j];
      if constexpr (EPI == 0){
        if (c < DI) out0[(size_t)r*DI + c] = siluf(fmaf(aux0[c*16 + 15], v, aux1[c]));
        else        out1[(size_t)r*DI + (c-DI)] = siluf(v);
      } else {
        out0[(size_t)r*DM + c] += v;
      }
    }
  }
}

// ---------- dbc split-K GEMM: part[ks][4096][80] = xi[:, ks*256:(ks+1)*256] @ Wx[ks*256:,...] ----------
__global__ __launch_bounds__(256) void k_dbc(const float* __restrict__ xi,
    const float* __restrict__ Wx, float* __restrict__ part){
  int r0 = blockIdx.x*64, k0 = blockIdx.y*256;
  int t = threadIdx.x, tx = t&15, ty = t>>4;
  __shared__ float As[64][65];   // [m][k]
  __shared__ float Ws[64][81];   // [k][n]
  float acc[4][5] = {};
  for (int kb=0; kb<256; kb+=64){
    int kbase = k0 + kb;
    __syncthreads();
    // stage A: 64 rows x 64 k
    for (int q=0;q<4;q++){
      int m = q*16 + ty;
      int kf = tx*4;
      float4 v = *(const float4*)(xi + (size_t)(r0+m)*DI + kbase + kf);
      As[m][kf+0]=v.x; As[m][kf+1]=v.y; As[m][kf+2]=v.z; As[m][kf+3]=v.w;
    }
    // stage Wx chunk: 64 k x 80 n
    for (int idx=t; idx<64*80; idx+=256){
      int kk = idx/80, n = idx%80;
      Ws[kk][n] = Wx[(size_t)(kbase+kk)*80 + n];
    }
    __syncthreads();
    #pragma unroll 4
    for (int kk=0;kk<64;kk++){
      float av[4], wv[5];
      #pragma unroll
      for (int i=0;i<4;i++) av[i] = As[ty*4+i][kk];
      #pragma unroll
      for (int j=0;j<5;j++) wv[j] = Ws[kk][tx*5+j];
      #pragma unroll
      for (int i=0;i<4;i++)
        #pragma unroll
        for (int j=0;j<5;j++) acc[i][j] = fmaf(av[i], wv[j], acc[i][j]);
    }
  }
  float* pp = part + (size_t)blockIdx.y*(BATCH*80) + (size_t)r0*80;
  #pragma unroll
  for (int i=0;i<4;i++)
    #pragma unroll
    for (int j=0;j<5;j++)
      pp[(ty*4+i)*80 + tx*5 + j] = acc[i][j];
}

// ---------- delta + gating: xi <- xi * (softplus(dbc[:16]@Wdt + bdt)*s + D) * sz ----------
__global__ __launch_bounds__(256) void k_delta_y2(const float* __restrict__ part,
    const float* __restrict__ Wdt, const float* __restrict__ bdt,
    const float* __restrict__ Dd, float* __restrict__ xi, const float* __restrict__ sz){
  int bid = blockIdx.x;
  int b = bid>>2, t = threadIdx.x;
  int e = ((bid&3)<<8) + t;
  __shared__ float dbc[80];
  __shared__ float s_sh;
  const size_t QP = (size_t)BATCH*80;
  if (t < 80){
    size_t o = (size_t)b*80 + t;
    dbc[t] = part[o] + part[QP+o] + part[2*QP+o] + part[3*QP+o];
  }
  __syncthreads();
  if (t < 64){
    float p = (t<32) ? dbc[16+t]*dbc[48+t] : 0.0f;
    #pragma unroll
    for (int o=32;o>0;o>>=1) p += __shfl_down(p,o);
    if (t==0) s_sh = p;
  }
  __syncthreads();
  float u = bdt[e];
  #pragma unroll
  for (int r=0;r<16;r++) u = fmaf(dbc[r], Wdt[r*DI + e], u);
  float delta = softplusf(u);
  size_t o = (size_t)b*DI + e;
  xi[o] = xi[o] * fmaf(delta, s_sh, Dd[e]) * sz[o];
}

// ---------- final: out = sigmoid(h @ Wf + bf) ----------
__global__ __launch_bounds__(64) void k_final(const float* __restrict__ h,
    const float* __restrict__ Wf, const float* __restrict__ bf, float* __restrict__ out){
  int b = blockIdx.x, t = threadIdx.x;
  float p = 0.0f;
  #pragma unroll
  for (int q=0;q<4;q++){ int c = q*64 + t; p = fmaf(h[(size_t)b*DM + c], Wf[c], p); }
  #pragma unroll
  for (int o=32;o>0;o>>=1) p += __shfl_down(p,o);
  if (t==0) out[b] = 1.0f/(1.0f + __expf(-(p + bf[0])));
}

extern "C" void kernel_launch(void* const* d_in, const int* in_sizes, int n_in,
                              void* d_out, int out_size, void* d_ws, size_t ws_size,
                              hipStream_t stream){
  const float* x   = (const float*)d_in[0];
  const float* Wp  = (const float*)d_in[1];
  const float* bp  = (const float*)d_in[2];
  const float* nw  = (const float*)d_in[3];
  const float* Win = (const float*)d_in[4];
  const float* cw  = (const float*)d_in[5];
  const float* cb  = (const float*)d_in[6];
  const float* Wx  = (const float*)d_in[7];
  const float* Wdt = (const float*)d_in[8];
  const float* bdt = (const float*)d_in[9];
  const float* Dd  = (const float*)d_in[11];   // A_log (d_in[10]) is dead: scan length 1, h0 = 0
  const float* Wout= (const float*)d_in[12];
  const float* Wf  = (const float*)d_in[13];
  const float* bf  = (const float*)d_in[14];
  float* out = (float*)d_out;

  float* ws = (float*)d_ws;
  float* h    = ws; ws += (size_t)BATCH*DM;
  float* xn   = ws; ws += (size_t)BATCH*DM;
  float* xib  = ws; ws += (size_t)BATCH*DI;
  float* szb  = ws; ws += (size_t)BATCH*DI;
  float* part = ws; // 4*BATCH*80

  k_proj_in<<<BATCH,256,0,stream>>>(x, Wp, bp, h);
  for (int l=0;l<NL;l++){
    k_rmsnorm<<<BATCH,256,0,stream>>>(h, nw + l*DM, xn);
    k_gemm<16,4,0><<<dim3(BATCH/64, (2*DI)/64),256,0,stream>>>(
        xn, Win + (size_t)l*DM*2*DI, DM, 2*DI,
        cw + (size_t)l*DI*16, cb + (size_t)l*DI, xib, szb);
    k_dbc<<<dim3(BATCH/64, 4),256,0,stream>>>(xib, Wx + (size_t)l*DI*80, part);
    k_delta_y2<<<(BATCH*DI)/256,256,0,stream>>>(part, Wdt + (size_t)l*16*DI,
        bdt + (size_t)l*DI, Dd + (size_t)l*DI, xib, szb);
    k_gemm<16,2,1><<<dim3(BATCH/32, DM/64),256,0,stream>>>(
        xib, Wout + (size_t)l*DI*DM, DI, DM,
        nullptr, nullptr, h, nullptr);
  }
  k_final<<<BATCH,64,0,stream>>>(h, Wf, bf, out);
}

// Round 2
// 381.607 us; speedup vs baseline: 1.9142x; 1.9142x over previous
//
#include <hip/hip_runtime.h>
#include <hip/hip_bf16.h>
#include <math.h>

#define BATCH 4096
#define IDIM 78
#define DM 256
#define DI 1024
#define NL 4

typedef __attribute__((ext_vector_type(8))) short bf16x8;
typedef __attribute__((ext_vector_type(4))) float f32x4;

__device__ __forceinline__ float siluf(float v){ return v / (1.0f + __expf(-v)); }
__device__ __forceinline__ float softplusf(float v){ return (v > 20.0f) ? v : log1pf(__expf(v)); }
__device__ __forceinline__ ushort f2bf(float f){
  union { float f; unsigned u; } c; c.f = f;
  unsigned r = c.u + 0x7fff + ((c.u >> 16) & 1);
  return (ushort)(r >> 16);
}
__device__ __forceinline__ float bf2f(ushort b){
  union { unsigned u; float f; } c; c.u = ((unsigned)b) << 16; return c.f;
}

// ---------- transpose + fp32->bf16 convert: dst[C][R] = bf16(src[R][C]), per-layer via z ----------
template<int R, int C>
__global__ __launch_bounds__(256) void k_tconv(const float* __restrict__ src, ushort* __restrict__ dst){
  __shared__ float tile[32][33];
  int c0 = blockIdx.x*32, r0 = blockIdx.y*32;
  src += (size_t)blockIdx.z * R * C;
  dst += (size_t)blockIdx.z * R * C;
  int t = threadIdx.x;
  int ci = t & 31, rq = t >> 5;
  #pragma unroll
  for (int p=0;p<4;p++){ int ri = p*8 + rq; tile[ri][ci] = src[(size_t)(r0+ri)*C + c0 + ci]; }
  __syncthreads();
  #pragma unroll
  for (int p=0;p<4;p++){ int ri = p*8 + rq; dst[(size_t)(c0+ri)*R + r0 + ci] = f2bf(tile[ci][ri]); }
}

// ---------- proj_in: h = x @ Wp + bp  (fp32, small) ----------
__global__ __launch_bounds__(256) void k_proj_in(const float* __restrict__ x,
    const float* __restrict__ Wp, const float* __restrict__ bp, float* __restrict__ h){
  int b = blockIdx.x, t = threadIdx.x;
  __shared__ float xs[IDIM];
  if (t < IDIM) xs[t] = x[b*IDIM + t];
  __syncthreads();
  float acc = bp[t];
  #pragma unroll
  for (int k=0;k<IDIM;k++) acc = fmaf(xs[k], Wp[k*DM + t], acc);
  h[b*DM + t] = acc;
}

// ---------- rmsnorm -> bf16 ----------
__global__ __launch_bounds__(256) void k_rmsnorm(const float* __restrict__ h,
    const float* __restrict__ nw, ushort* __restrict__ xn){
  int b = blockIdx.x, t = threadIdx.x;
  float v = h[b*DM + t];
  float ss = v*v;
  #pragma unroll
  for (int o=32;o>0;o>>=1) ss += __shfl_down(ss, o);
  __shared__ float red[4];
  if ((t&63)==0) red[t>>6] = ss;
  __syncthreads();
  float tot = red[0]+red[1]+red[2]+red[3];
  float sc = rsqrtf(tot*(1.0f/DM) + 1e-5f);
  xn[b*DM + t] = f2bf(v*sc*nw[t]);
}

// ---------- bf16 MFMA GEMM: C[M][N] = A[M][K] @ Bt[N][K]^T, BK=32, 4 waves (2x2) ----------
// EPI=0: conv+silu -> xi (col<DI) / silu -> sz (col>=DI), both bf16
// EPI=1: outf[row*DM+col] += acc (fp32 residual accumulate)
template<int FM, int FN, int EPI>
__global__ __launch_bounds__(256) void k_mgemm(
    const ushort* __restrict__ A, const ushort* __restrict__ Bt, int K,
    const float* __restrict__ aux0, const float* __restrict__ aux1,
    float* __restrict__ outf, ushort* __restrict__ out0, ushort* __restrict__ out1)
{
  constexpr int BM = 2*FM*16, BN = 2*FN*16;
  __shared__ __align__(16) ushort As[BM][40];
  __shared__ __align__(16) ushort Bs[BN][40];
  int t = threadIdx.x;
  int row0 = blockIdx.x*BM, col0 = blockIdx.y*BN;
  int wid = t>>6, lane = t&63;
  int wr = wid>>1, wc = wid&1;
  int lr = lane&15, lk = lane>>4;
  f32x4 acc[FM][FN] = {};

  for (int k0=0;k0<K;k0+=32){
    #pragma unroll
    for (int it=0; it<BM/64; ++it){
      int r = it*64 + (t>>2), sg = t&3;
      uint4 v = *(const uint4*)(A + (size_t)(row0 + r)*K + k0 + sg*8);
      *(uint4*)&As[r][sg*8] = v;
    }
    #pragma unroll
    for (int it=0; it<BN/64; ++it){
      int r = it*64 + (t>>2), sg = t&3;
      uint4 v = *(const uint4*)(Bt + (size_t)(col0 + r)*K + k0 + sg*8);
      *(uint4*)&Bs[r][sg*8] = v;
    }
    __syncthreads();
    bf16x8 av[FM], bv[FN];
    #pragma unroll
    for (int i=0;i<FM;i++) av[i] = *(const bf16x8*)&As[wr*FM*16 + i*16 + lr][lk*8];
    #pragma unroll
    for (int j=0;j<FN;j++) bv[j] = *(const bf16x8*)&Bs[wc*FN*16 + j*16 + lr][lk*8];
    #pragma unroll
    for (int i=0;i<FM;i++)
      #pragma unroll
      for (int j=0;j<FN;j++)
        acc[i][j] = __builtin_amdgcn_mfma_f32_16x16x32_bf16(av[i], bv[j], acc[i][j], 0, 0, 0);
    __syncthreads();
  }

  #pragma unroll
  for (int i=0;i<FM;i++){
    #pragma unroll
    for (int j=0;j<FN;j++){
      int colb = col0 + wc*FN*16 + j*16 + lr;
      #pragma unroll
      for (int r=0;r<4;r++){
        int rowb = row0 + wr*FM*16 + i*16 + lk*4 + r;
        float v = acc[i][j][r];
        if constexpr (EPI==0){
          if (colb < DI) out0[(size_t)rowb*DI + colb] = f2bf(siluf(fmaf(aux0[colb*16+15], v, aux1[colb])));
          else           out1[(size_t)rowb*DI + colb - DI] = f2bf(siluf(v));
        } else {
          outf[(size_t)rowb*DM + colb] += v;
        }
      }
    }
  }
}

// ---------- dbc split-K GEMM: part[ks][4096][80] = xi[:, ks*256:(ks+1)*256] @ Wx[ks*256:,...] ----------
__global__ __launch_bounds__(256) void k_dbc(const ushort* __restrict__ xi,
    const float* __restrict__ Wx, float* __restrict__ part){
  int r0 = blockIdx.x*64, k0 = blockIdx.y*256;
  int t = threadIdx.x, tx = t&15, ty = t>>4;
  __shared__ float As[64][65];   // [m][k]
  __shared__ float Ws[64][81];   // [k][n]
  float acc[4][5] = {};
  for (int kb=0; kb<256; kb+=64){
    int kbase = k0 + kb;
    __syncthreads();
    #pragma unroll
    for (int p=0;p<2;p++){
      int m = p*32 + (t>>3), kf = (t&7)*8;
      uint4 v = *(const uint4*)(xi + (size_t)(r0+m)*DI + kbase + kf);
      const ushort* pv = (const ushort*)&v;
      #pragma unroll
      for (int q=0;q<8;q++) As[m][kf+q] = bf2f(pv[q]);
    }
    for (int idx=t; idx<64*80; idx+=256){
      int kk = idx/80, n = idx%80;
      Ws[kk][n] = Wx[(size_t)(kbase+kk)*80 + n];
    }
    __syncthreads();
    #pragma unroll 4
    for (int kk=0;kk<64;kk++){
      float av[4], wv[5];
      #pragma unroll
      for (int i=0;i<4;i++) av[i] = As[ty*4+i][kk];
      #pragma unroll
      for (int j=0;j<5;j++) wv[j] = Ws[kk][tx*5+j];
      #pragma unroll
      for (int i=0;i<4;i++)
        #pragma unroll
        for (int j=0;j<5;j++) acc[i][j] = fmaf(av[i], wv[j], acc[i][j]);
    }
  }
  float* pp = part + (size_t)blockIdx.y*(BATCH*80) + (size_t)r0*80;
  #pragma unroll
  for (int i=0;i<4;i++)
    #pragma unroll
    for (int j=0;j<5;j++)
      pp[(ty*4+i)*80 + tx*5 + j] = acc[i][j];
}

// ---------- delta + gating: y = xi * (softplus(dbc[:16]@Wdt + bdt)*s + D) * sz, bf16 out ----------
__global__ __launch_bounds__(256) void k_delta_y2(const float* __restrict__ part,
    const float* __restrict__ Wdt, const float* __restrict__ bdt,
    const float* __restrict__ Dd, const ushort* __restrict__ xi,
    const ushort* __restrict__ sz, ushort* __restrict__ y){
  int bid = blockIdx.x;
  int b = bid>>2, t = threadIdx.x;
  int e = ((bid&3)<<8) + t;
  __shared__ float dbc[80];
  __shared__ float s_sh;
  const size_t QP = (size_t)BATCH*80;
  if (t < 80){
    size_t o = (size_t)b*80 + t;
    dbc[t] = part[o] + part[QP+o] + part[2*QP+o] + part[3*QP+o];
  }
  __syncthreads();
  if (t < 64){
    float p = (t<32) ? dbc[16+t]*dbc[48+t] : 0.0f;
    #pragma unroll
    for (int o=32;o>0;o>>=1) p += __shfl_down(p,o);
    if (t==0) s_sh = p;
  }
  __syncthreads();
  float u = bdt[e];
  #pragma unroll
  for (int r=0;r<16;r++) u = fmaf(dbc[r], Wdt[r*DI + e], u);
  float delta = softplusf(u);
  size_t o = (size_t)b*DI + e;
  y[o] = f2bf(bf2f(xi[o]) * fmaf(delta, s_sh, Dd[e]) * bf2f(sz[o]));
}

// ---------- final: out = sigmoid(h @ Wf + bf) ----------
__global__ __launch_bounds__(64) void k_final(const float* __restrict__ h,
    const float* __restrict__ Wf, const float* __restrict__ bf, float* __restrict__ out){
  int b = blockIdx.x, t = threadIdx.x;
  float p = 0.0f;
  #pragma unroll
  for (int q=0;q<4;q++){ int c = q*64 + t; p = fmaf(h[(size_t)b*DM + c], Wf[c], p); }
  #pragma unroll
  for (int o=32;o>0;o>>=1) p += __shfl_down(p,o);
  if (t==0) out[b] = 1.0f/(1.0f + __expf(-(p + bf[0])));
}

extern "C" void kernel_launch(void* const* d_in, const int* in_sizes, int n_in,
                              void* d_out, int out_size, void* d_ws, size_t ws_size,
                              hipStream_t stream){
  const float* x   = (const float*)d_in[0];
  const float* Wp  = (const float*)d_in[1];
  const float* bp  = (const float*)d_in[2];
  const float* nw  = (const float*)d_in[3];
  const float* Win = (const float*)d_in[4];
  const float* cw  = (const float*)d_in[5];
  const float* cb  = (const float*)d_in[6];
  const float* Wx  = (const float*)d_in[7];
  const float* Wdt = (const float*)d_in[8];
  const float* bdt = (const float*)d_in[9];
  const float* Dd  = (const float*)d_in[11];   // A_log (d_in[10]) is dead: scan length 1, h0 = 0
  const float* Wout= (const float*)d_in[12];
  const float* Wf  = (const float*)d_in[13];
  const float* bf  = (const float*)d_in[14];
  float* out = (float*)d_out;

  char* wsb = (char*)d_ws;
  float*  h    = (float*)wsb;  wsb += (size_t)BATCH*DM*4;          // 4 MB
  ushort* xn   = (ushort*)wsb; wsb += (size_t)BATCH*DM*2;          // 2 MB
  ushort* xi   = (ushort*)wsb; wsb += (size_t)BATCH*DI*2;          // 8 MB
  ushort* sz   = (ushort*)wsb; wsb += (size_t)BATCH*DI*2;          // 8 MB
  ushort* y    = (ushort*)wsb; wsb += (size_t)BATCH*DI*2;          // 8 MB
  float*  part = (float*)wsb;  wsb += (size_t)4*BATCH*80*4;        // 5.25 MB
  ushort* WinT = (ushort*)wsb; wsb += (size_t)NL*2*DI*DM*2;        // 4 MB
  ushort* WoutT= (ushort*)wsb; wsb += (size_t)NL*DM*DI*2;          // 2 MB

  // weight prep: WinT[l][2048][256], WoutT[l][256][1024]
  k_tconv<DM, 2*DI><<<dim3(2*DI/32, DM/32, NL), 256, 0, stream>>>(Win, WinT);
  k_tconv<DI, DM><<<dim3(DM/32, DI/32, NL), 256, 0, stream>>>(Wout, WoutT);

  k_proj_in<<<BATCH,256,0,stream>>>(x, Wp, bp, h);
  for (int l=0;l<NL;l++){
    k_rmsnorm<<<BATCH,256,0,stream>>>(h, nw + l*DM, xn);
    k_mgemm<4,4,0><<<dim3(BATCH/128, (2*DI)/128),256,0,stream>>>(
        xn, WinT + (size_t)l*2*DI*DM, DM,
        cw + (size_t)l*DI*16, cb + (size_t)l*DI, nullptr, xi, sz);
    k_dbc<<<dim3(BATCH/64, 4),256,0,stream>>>(xi, Wx + (size_t)l*DI*80, part);
    k_delta_y2<<<(BATCH*DI)/256,256,0,stream>>>(part, Wdt + (size_t)l*16*DI,
        bdt + (size_t)l*DI, Dd + (size_t)l*DI, xi, sz, y);
    k_mgemm<2,2,1><<<dim3(BATCH/64, DM/64),256,0,stream>>>(
        y, WoutT + (size_t)l*DM*DI, DI,
        nullptr, nullptr, h, nullptr, nullptr);
  }
  k_final<<<BATCH,64,0,stream>>>(h, Wf, bf, out);
}

// Round 3
// 302.127 us; speedup vs baseline: 2.4177x; 1.2631x over previous
//
#include <hip/hip_runtime.h>
#include <hip/hip_bf16.h>
#include <math.h>

#define BATCH 4096
#define IDIM 78
#define DM 256
#define DI 1024
#define NL 4

typedef __attribute__((ext_vector_type(8))) short bf16x8;
typedef __attribute__((ext_vector_type(4))) float f32x4;

__device__ __forceinline__ float siluf(float v){ return v / (1.0f + __expf(-v)); }
__device__ __forceinline__ float softplusf(float v){ return (v > 20.0f) ? v : log1pf(__expf(v)); }
__device__ __forceinline__ ushort f2bf(float f){
  union { float f; unsigned u; } c; c.f = f;
  unsigned r = c.u + 0x7fff + ((c.u >> 16) & 1);
  return (ushort)(r >> 16);
}
__device__ __forceinline__ float bf2f(ushort b){
  union { unsigned u; float f; } c; c.u = ((unsigned)b) << 16; return c.f;
}
// async global->LDS, 16B per lane; LDS dest is wave-uniform base + lane*16
__device__ __forceinline__ void async_copy16(void* lds, const void* g){
  __builtin_amdgcn_global_load_lds(
      (const __attribute__((address_space(1))) unsigned int*)g,
      (__attribute__((address_space(3))) unsigned int*)lds, 16, 0, 0);
}

// ---------- transpose + fp32->bf16: dst[C][R] = bf16(src[R][C]) ----------
template<int R, int C>
__global__ __launch_bounds__(256) void k_tconv(const float* __restrict__ src, ushort* __restrict__ dst){
  __shared__ float tile[32][33];
  int c0 = blockIdx.x*32, r0 = blockIdx.y*32;
  src += (size_t)blockIdx.z * R * C;
  dst += (size_t)blockIdx.z * R * C;
  int t = threadIdx.x;
  int ci = t & 31, rq = t >> 5;
  #pragma unroll
  for (int p=0;p<4;p++){ int ri = p*8 + rq; tile[ri][ci] = src[(size_t)(r0+ri)*C + c0 + ci]; }
  __syncthreads();
  #pragma unroll
  for (int p=0;p<4;p++){ int ri = p*8 + rq; dst[(size_t)(c0+ri)*R + r0 + ci] = f2bf(tile[ci][ri]); }
}

// ---------- WxT[l][80][1024] = bf16(Wx[l][1024][80]^T) ----------
__global__ __launch_bounds__(256) void k_wxT(const float* __restrict__ Wx, ushort* __restrict__ WxT){
  int l = blockIdx.z;
  int n = blockIdx.y;
  int k = blockIdx.x*256 + threadIdx.x;
  WxT[(size_t)l*80*DI + (size_t)n*DI + k] = f2bf(Wx[(size_t)l*DI*80 + (size_t)k*80 + n]);
}

// ---------- proj_in + rmsnorm(layer0): h = x@Wp+bp ; xn = rms(h)*nw ----------
__global__ __launch_bounds__(256) void k_proj_in(const float* __restrict__ x,
    const float* __restrict__ Wp, const float* __restrict__ bp,
    const float* __restrict__ nw, float* __restrict__ h, ushort* __restrict__ xn){
  int b = blockIdx.x, t = threadIdx.x;
  __shared__ float xs[IDIM];
  if (t < IDIM) xs[t] = x[b*IDIM + t];
  __syncthreads();
  float acc = bp[t];
  #pragma unroll
  for (int k=0;k<IDIM;k++) acc = fmaf(xs[k], Wp[k*DM + t], acc);
  h[b*DM + t] = acc;
  float ss = acc*acc;
  #pragma unroll
  for (int o=32;o>0;o>>=1) ss += __shfl_down(ss, o);
  __shared__ float red[4];
  if ((t&63)==0) red[t>>6] = ss;
  __syncthreads();
  float tot = red[0]+red[1]+red[2]+red[3];
  float sc = rsqrtf(tot*(1.0f/DM) + 1e-5f);
  xn[b*DM + t] = f2bf(acc*sc*nw[t]);
}

// ---------- rmsnorm -> bf16 ----------
__global__ __launch_bounds__(256) void k_rmsnorm(const float* __restrict__ h,
    const float* __restrict__ nw, ushort* __restrict__ xn){
  int b = blockIdx.x, t = threadIdx.x;
  float v = h[b*DM + t];
  float ss = v*v;
  #pragma unroll
  for (int o=32;o>0;o>>=1) ss += __shfl_down(ss, o);
  __shared__ float red[4];
  if ((t&63)==0) red[t>>6] = ss;
  __syncthreads();
  float tot = red[0]+red[1]+red[2]+red[3];
  float sc = rsqrtf(tot*(1.0f/DM) + 1e-5f);
  xn[b*DM + t] = f2bf(v*sc*nw[t]);
}

// ---------- bf16 MFMA GEMM, global_load_lds staging, XOR-4 swizzled LDS ----------
// C[M][N] = A[M][K] @ Bt[N][K]^T ; 4 waves (2x2); BK=32
// EPI=0: conv+silu -> out0 (col<DI) / silu -> out1 ; EPI=1: outf += acc
template<int FM, int FN, int EPI>
__global__ __launch_bounds__(256) void k_mgemm(
    const ushort* __restrict__ A, const ushort* __restrict__ Bt, int K,
    const float* __restrict__ aux0, const float* __restrict__ aux1,
    float* __restrict__ outf, ushort* __restrict__ out0, ushort* __restrict__ out1)
{
  constexpr int BM = 2*FM*16, BN = 2*FN*16;
  __shared__ __align__(16) ushort As[BM][32];
  __shared__ __align__(16) ushort Bs[BN][32];
  int t = threadIdx.x;
  int row0 = blockIdx.x*BM, col0 = blockIdx.y*BN;
  int wid = t>>6, lane = t&63;
  int wr = wid>>1, wc = wid&1;
  int lr = lane&15, lk = lane>>4;
  // staging geometry: lane covers (row = i*16 + sr, 16B slot sc); source chunk XOR-swizzled
  int sr = lane>>2, sc = lane&3;
  int gch = sc ^ (sr&3);
  f32x4 acc[FM][FN] = {};

  const ushort* Abase = A  + (size_t)(row0 + sr)*K + gch*8;
  const ushort* Bbase = Bt + (size_t)(col0 + sr)*K + gch*8;
  int rsw = (lk ^ (lr&3))*8;   // swizzled read chunk offset (row&3 == lr&3 for 16-aligned frag rows)

  for (int k0=0;k0<K;k0+=32){
    #pragma unroll
    for (int q=0;q<BM/64;q++){ int i = q*4 + wid; async_copy16(&As[i*16][0], Abase + (size_t)i*16*K + k0); }
    #pragma unroll
    for (int q=0;q<BN/64;q++){ int i = q*4 + wid; async_copy16(&Bs[i*16][0], Bbase + (size_t)i*16*K + k0); }
    __syncthreads();
    bf16x8 av[FM], bv[FN];
    #pragma unroll
    for (int i=0;i<FM;i++) av[i] = *(const bf16x8*)&As[wr*FM*16 + i*16 + lr][rsw];
    #pragma unroll
    for (int j=0;j<FN;j++) bv[j] = *(const bf16x8*)&Bs[wc*FN*16 + j*16 + lr][rsw];
    #pragma unroll
    for (int i=0;i<FM;i++)
      #pragma unroll
      for (int j=0;j<FN;j++)
        acc[i][j] = __builtin_amdgcn_mfma_f32_16x16x32_bf16(av[i], bv[j], acc[i][j], 0, 0, 0);
    __syncthreads();
  }

  #pragma unroll
  for (int i=0;i<FM;i++){
    #pragma unroll
    for (int j=0;j<FN;j++){
      int colb = col0 + wc*FN*16 + j*16 + lr;
      #pragma unroll
      for (int r=0;r<4;r++){
        int rowb = row0 + wr*FM*16 + i*16 + lk*4 + r;
        float v = acc[i][j][r];
        if constexpr (EPI==0){
          if (colb < DI) out0[(size_t)rowb*DI + colb] = f2bf(siluf(fmaf(aux0[colb*16+15], v, aux1[colb])));
          else           out1[(size_t)rowb*DI + colb - DI] = f2bf(siluf(v));
        } else {
          outf[(size_t)rowb*DM + colb] += v;
        }
      }
    }
  }
}

// ---------- dbc via MFMA: part[ks][4096][80] = xi[:, ks*256:+256] @ WxT^T ----------
__global__ __launch_bounds__(256) void k_dbc(const ushort* __restrict__ xi,
    const ushort* __restrict__ WxT, float* __restrict__ part){
  __shared__ __align__(16) ushort As[64][32];
  __shared__ __align__(16) ushort Bs[80][32];
  int r0 = blockIdx.x*64, k0 = blockIdx.y*256;
  int t = threadIdx.x, wid = t>>6, lane = t&63;
  int lr = lane&15, lk = lane>>4;
  int sr = lane>>2, sc = lane&3;
  int gch = sc ^ (sr&3);
  int rsw = (lk ^ (lr&3))*8;
  f32x4 acc[5] = {};
  const ushort* Ab = xi  + (size_t)(r0 + sr)*DI + k0 + gch*8;
  const ushort* Bb = WxT + (size_t)sr*DI + k0 + gch*8;
  for (int kb=0; kb<256; kb+=32){
    async_copy16(&As[wid*16][0], Ab + (size_t)wid*16*DI + kb);
    #pragma unroll
    for (int q=0;q<2;q++){ int i = q*4 + wid; if (i < 5) async_copy16(&Bs[i*16][0], Bb + (size_t)i*16*DI + kb); }
    __syncthreads();
    bf16x8 a = *(const bf16x8*)&As[wid*16 + lr][rsw];
    #pragma unroll
    for (int j=0;j<5;j++){
      bf16x8 b = *(const bf16x8*)&Bs[j*16 + lr][rsw];
      acc[j] = __builtin_amdgcn_mfma_f32_16x16x32_bf16(a, b, acc[j], 0, 0, 0);
    }
    __syncthreads();
  }
  float* pp = part + (size_t)blockIdx.y*(BATCH*80) + (size_t)r0*80;
  #pragma unroll
  for (int j=0;j<5;j++){
    int n = j*16 + lr;
    #pragma unroll
    for (int r=0;r<4;r++){
      int row = wid*16 + lk*4 + r;
      pp[(size_t)row*80 + n] = acc[j][r];
    }
  }
}

// ---------- delta + gating: y = xi * (softplus(dbc[:16]@Wdt + bdt)*s + D) * sz ----------
__global__ __launch_bounds__(256) void k_delta_y2(const float* __restrict__ part,
    const float* __restrict__ Wdt, const float* __restrict__ bdt,
    const float* __restrict__ Dd, const ushort* __restrict__ xi,
    const ushort* __restrict__ sz, ushort* __restrict__ y){
  int bid = blockIdx.x;
  int b = bid>>2, t = threadIdx.x;
  int e = ((bid&3)<<8) + t;
  __shared__ float dbc[80];
  __shared__ float s_sh;
  const size_t QP = (size_t)BATCH*80;
  if (t < 80){
    size_t o = (size_t)b*80 + t;
    dbc[t] = part[o] + part[QP+o] + part[2*QP+o] + part[3*QP+o];
  }
  __syncthreads();
  if (t < 64){
    float p = (t<32) ? dbc[16+t]*dbc[48+t] : 0.0f;
    #pragma unroll
    for (int o=32;o>0;o>>=1) p += __shfl_down(p,o);
    if (t==0) s_sh = p;
  }
  __syncthreads();
  float u = bdt[e];
  #pragma unroll
  for (int r=0;r<16;r++) u = fmaf(dbc[r], Wdt[r*DI + e], u);
  float delta = softplusf(u);
  size_t o = (size_t)b*DI + e;
  y[o] = f2bf(bf2f(xi[o]) * fmaf(delta, s_sh, Dd[e]) * bf2f(sz[o]));
}

// ---------- final: out = sigmoid(h @ Wf + bf) ----------
__global__ __launch_bounds__(64) void k_final(const float* __restrict__ h,
    const float* __restrict__ Wf, const float* __restrict__ bf, float* __restrict__ out){
  int b = blockIdx.x, t = threadIdx.x;
  float p = 0.0f;
  #pragma unroll
  for (int q=0;q<4;q++){ int c = q*64 + t; p = fmaf(h[(size_t)b*DM + c], Wf[c], p); }
  #pragma unroll
  for (int o=32;o>0;o>>=1) p += __shfl_down(p,o);
  if (t==0) out[b] = 1.0f/(1.0f + __expf(-(p + bf[0])));
}

extern "C" void kernel_launch(void* const* d_in, const int* in_sizes, int n_in,
                              void* d_out, int out_size, void* d_ws, size_t ws_size,
                              hipStream_t stream){
  const float* x   = (const float*)d_in[0];
  const float* Wp  = (const float*)d_in[1];
  const float* bp  = (const float*)d_in[2];
  const float* nw  = (const float*)d_in[3];
  const float* Win = (const float*)d_in[4];
  const float* cw  = (const float*)d_in[5];
  const float* cb  = (const float*)d_in[6];
  const float* Wx  = (const float*)d_in[7];
  const float* Wdt = (const float*)d_in[8];
  const float* bdt = (const float*)d_in[9];
  const float* Dd  = (const float*)d_in[11];   // A_log (d_in[10]) is dead: scan length 1, h0 = 0
  const float* Wout= (const float*)d_in[12];
  const float* Wf  = (const float*)d_in[13];
  const float* bf  = (const float*)d_in[14];
  float* out = (float*)d_out;

  char* wsb = (char*)d_ws;
  float*  h    = (float*)wsb;  wsb += (size_t)BATCH*DM*4;          // 4 MB
  ushort* xn   = (ushort*)wsb; wsb += (size_t)BATCH*DM*2;          // 2 MB
  ushort* xi   = (ushort*)wsb; wsb += (size_t)BATCH*DI*2;          // 8 MB
  ushort* sz   = (ushort*)wsb; wsb += (size_t)BATCH*DI*2;          // 8 MB
  ushort* y    = (ushort*)wsb; wsb += (size_t)BATCH*DI*2;          // 8 MB
  float*  part = (float*)wsb;  wsb += (size_t)4*BATCH*80*4;        // 5.25 MB
  ushort* WinT = (ushort*)wsb; wsb += (size_t)NL*2*DI*DM*2;        // 4 MB
  ushort* WoutT= (ushort*)wsb; wsb += (size_t)NL*DM*DI*2;          // 2 MB
  ushort* WxT  = (ushort*)wsb; wsb += (size_t)NL*80*DI*2;          // 0.64 MB

  // weight prep
  k_tconv<DM, 2*DI><<<dim3(2*DI/32, DM/32, NL), 256, 0, stream>>>(Win, WinT);
  k_tconv<DI, DM><<<dim3(DM/32, DI/32, NL), 256, 0, stream>>>(Wout, WoutT);
  k_wxT<<<dim3(DI/256, 80, NL), 256, 0, stream>>>(Wx, WxT);

  k_proj_in<<<BATCH,256,0,stream>>>(x, Wp, bp, nw, h, xn);
  for (int l=0;l<NL;l++){
    if (l > 0) k_rmsnorm<<<BATCH,256,0,stream>>>(h, nw + l*DM, xn);
    k_mgemm<4,4,0><<<dim3(BATCH/128, (2*DI)/128),256,0,stream>>>(
        xn, WinT + (size_t)l*2*DI*DM, DM,
        cw + (size_t)l*DI*16, cb + (size_t)l*DI, nullptr, xi, sz);
    k_dbc<<<dim3(BATCH/64, 4),256,0,stream>>>(xi, WxT + (size_t)l*80*DI, part);
    k_delta_y2<<<(BATCH*DI)/256,256,0,stream>>>(part, Wdt + (size_t)l*16*DI,
        bdt + (size_t)l*DI, Dd + (size_t)l*DI, xi, sz, y);
    k_mgemm<2,2,1><<<dim3(BATCH/64, DM/64),256,0,stream>>>(
        y, WoutT + (size_t)l*DM*DI, DI,
        nullptr, nullptr, h, nullptr, nullptr);
  }
  k_final<<<BATCH,64,0,stream>>>(h, Wf, bf, out);
}